// Round 8
// baseline (321.092 us; speedup 1.0000x reference)
//
#include <hip/hip_runtime.h>
#include <hip/hip_bf16.h>
#include <stdint.h>
#include <stddef.h>

#define S_LEN 2048
#define HID_DIM 2048
#define NH 16
#define D_QK 192
#define D_NOPE 128
#define D_ROPE 64
#define D_V 128
#define KV_R 512
#define CKV_N (KV_R + D_ROPE)            /* 576 */
#define KVB_N (NH * (D_NOPE + D_V))      /* 4096 */
#define QN (NH * D_QK)                   /* 3072 */
#define CAT_N (QN + CKV_N)               /* 3648: q_proj+kv_a fused N */
#define SCALING 0.07216878364870322f     /* 192^-0.5 */

typedef __attribute__((ext_vector_type(8))) short short8;
typedef __attribute__((ext_vector_type(4))) short short4v;
typedef __attribute__((ext_vector_type(4))) float f32x4;

__device__ __forceinline__ short f2bf_bits(float f) {
  unsigned u = __float_as_uint(f);
  unsigned r = (u + 0x7fffu + ((u >> 16) & 1u)) >> 16;  // RNE
  return (short)(r & 0xffffu);
}
__device__ __forceinline__ float bf2f(short b) {
  return __uint_as_float(((unsigned)(unsigned short)b) << 16);
}

__device__ __forceinline__ f32x4 mfma_bf16(short8 a, short8 b, f32x4 c) {
  return __builtin_amdgcn_mfma_f32_16x16x32_bf16(a, b, c, 0, 0, 0);
}

// ---------------------------------------------------------------------------
// Fused f32 -> bf16 conversion of 5 tensors in one launch.
// ---------------------------------------------------------------------------
__global__ __launch_bounds__(256)
void cvt5_k(const float* __restrict__ s0, short* __restrict__ d0, int c0,
            const float* __restrict__ s1, short* __restrict__ d1, int c1,
            const float* __restrict__ s2, short* __restrict__ d2, int c2,
            const float* __restrict__ s3, short* __restrict__ d3, int c3,
            const float* __restrict__ s4, short* __restrict__ d4, int c4) {
  const int i = blockIdx.x * 256 + threadIdx.x;
  const float* s; short* d; int base;
  if      (i < c0) { s = s0; d = d0; base = 0;  }
  else if (i < c1) { s = s1; d = d1; base = c0; }
  else if (i < c2) { s = s2; d = d2; base = c1; }
  else if (i < c3) { s = s3; d = d3; base = c2; }
  else if (i < c4) { s = s4; d = d4; base = c3; }
  else return;
  const int j = i - base;
  const float4 v = ((const float4*)s)[j];
  short4v o;
  o.x = f2bf_bits(v.x); o.y = f2bf_bits(v.y);
  o.z = f2bf_bits(v.z); o.w = f2bf_bits(v.w);
  ((short4v*)d)[j] = o;
}

// ---------------------------------------------------------------------------
// C[M,N] = A[M,K] @ B[N,K]^T   (A,B bf16 bits, f32 accum). BK=64 (2x m97).
// ---------------------------------------------------------------------------
template <bool OUTF32>
__global__ __launch_bounds__(256, 3)
void gemm_bt(const short* __restrict__ A, const short* __restrict__ B,
             void* __restrict__ Cv, int M, int N, int K) {
  __shared__ short sA[2][128 * 32];
  __shared__ short sB[2][128 * 32];
  const int tid  = threadIdx.x;
  const int wave = tid >> 6;
  const int lane = tid & 63;
  const int bm = blockIdx.y * 128;
  const int bn = blockIdx.x * 128;
  const int wr = wave >> 1, wc = wave & 1;
  const int fr = lane & 15, fk = (lane >> 4) * 8;
  const int srow = lane >> 2;
  const int scol = (lane & 3) * 8;

  f32x4 acc[4][4];
  for (int i = 0; i < 4; ++i)
    for (int j = 0; j < 4; ++j)
      for (int r = 0; r < 4; ++r) acc[i][j][r] = 0.f;

  for (int k0 = 0; k0 < K; k0 += 64) {
    __syncthreads();
#pragma unroll
    for (int cc = 0; cc < 2; ++cc) {
      const int c = wave * 2 + cc;
      const int ar = bm + c * 16 + srow;
      int br = bn + c * 16 + srow; if (br > N - 1) br = N - 1;
#pragma unroll
      for (int kh = 0; kh < 2; ++kh) {
        __builtin_amdgcn_global_load_lds(
            (const __attribute__((address_space(1))) void*)(A + (size_t)ar * K + k0 + kh * 32 + scol),
            (__attribute__((address_space(3))) void*)(sA[kh] + c * 512), 16, 0, 0);
        __builtin_amdgcn_global_load_lds(
            (const __attribute__((address_space(1))) void*)(B + (size_t)br * K + k0 + kh * 32 + scol),
            (__attribute__((address_space(3))) void*)(sB[kh] + c * 512), 16, 0, 0);
      }
    }
    __syncthreads();
#pragma unroll
    for (int kh = 0; kh < 2; ++kh) {
      short8 af[4], bfr[4];
#pragma unroll
      for (int i = 0; i < 4; ++i)
        af[i] = *(const short8*)(sA[kh] + (wr * 64 + i * 16 + fr) * 32 + fk);
#pragma unroll
      for (int j = 0; j < 4; ++j)
        bfr[j] = *(const short8*)(sB[kh] + (wc * 64 + j * 16 + fr) * 32 + fk);
#pragma unroll
      for (int i = 0; i < 4; ++i)
#pragma unroll
        for (int j = 0; j < 4; ++j)
          acc[i][j] = mfma_bf16(af[i], bfr[j], acc[i][j]);
    }
  }

  const int cr = (lane >> 4) * 4, ccol = lane & 15;
#pragma unroll
  for (int i = 0; i < 4; ++i)
#pragma unroll
    for (int j = 0; j < 4; ++j) {
      const int col = bn + wc * 64 + j * 16 + ccol;
      if (col < N) {
#pragma unroll
        for (int r = 0; r < 4; ++r) {
          const int row = bm + wr * 64 + i * 16 + cr + r;
          if (OUTF32)
            ((float*)Cv)[(size_t)row * N + col] = acc[i][j][r];
          else
            ((short*)Cv)[(size_t)row * N + col] = f2bf_bits(acc[i][j][r]);
        }
      }
    }
}

// ---------------------------------------------------------------------------
// RMSNorm over qckv[:, 3072:3584] -> ckvn (bf16).
// ---------------------------------------------------------------------------
__global__ __launch_bounds__(256)
void rmsnorm_k(const short* __restrict__ qckv, const float* __restrict__ w,
               short* __restrict__ out) {
  const int s = blockIdx.x, t = threadIdx.x;
  const short* x = qckv + (size_t)s * CAT_N + QN;
  float v0 = bf2f(x[2 * t]), v1 = bf2f(x[2 * t + 1]);
  float ss = v0 * v0 + v1 * v1;
#pragma unroll
  for (int off = 1; off < 64; off <<= 1) ss += __shfl_xor(ss, off, 64);
  __shared__ float red[4];
  if ((t & 63) == 0) red[t >> 6] = ss;
  __syncthreads();
  const float tot = red[0] + red[1] + red[2] + red[3];
  const float sc = rsqrtf(tot * (1.0f / 512.0f) + 1e-6f);
  out[(size_t)s * KV_R + 2 * t]     = f2bf_bits(v0 * sc * w[2 * t]);
  out[(size_t)s * KV_R + 2 * t + 1] = f2bf_bits(v1 * sc * w[2 * t + 1]);
}

// ---------------------------------------------------------------------------
// Prep: RoPE (deinterleaved) + assemble Qs[h][s][192], Ks[h][s][192].
// ---------------------------------------------------------------------------
__global__ __launch_bounds__(256)
void prep_k(const short* __restrict__ qckv, const short* __restrict__ kvb,
            const float* __restrict__ cosb, const float* __restrict__ sinb,
            short* __restrict__ Qs, short* __restrict__ Ks) {
  const int s = blockIdx.x, t = threadIdx.x;
  const short* qrow = qckv + (size_t)s * CAT_N;
  __shared__ float cs[32], sn[32];
  __shared__ short krs[64];
  if (t < 32) {
    const float c  = cosb[(size_t)s * 64 + t];
    const float si = sinb[(size_t)s * 64 + t];
    cs[t] = c; sn[t] = si;
    const float e0 = bf2f(qrow[QN + KV_R + 2 * t]);
    const float e1 = bf2f(qrow[QN + KV_R + 2 * t + 1]);
    krs[t]      = f2bf_bits(e0 * c - e1 * si);
    krs[t + 32] = f2bf_bits(e1 * c + e0 * si);
  }
  __syncthreads();
  const int h = t >> 4, i = t & 15;
  *(short8*)(Qs + ((size_t)h * S_LEN + s) * D_QK + i * 8) =
      *(const short8*)(qrow + h * D_QK + i * 8);
  *(short8*)(Ks + ((size_t)h * S_LEN + s) * D_QK + i * 8) =
      *(const short8*)(kvb + (size_t)s * KVB_N + h * 256 + i * 8);
#pragma unroll
  for (int p = 0; p < 2; ++p) {
    const int ii = i * 2 + p;  // 0..31
    const float e0 = bf2f(qrow[h * D_QK + 128 + 2 * ii]);
    const float e1 = bf2f(qrow[h * D_QK + 128 + 2 * ii + 1]);
    Qs[((size_t)h * S_LEN + s) * D_QK + 128 + ii] = f2bf_bits(e0 * cs[ii] - e1 * sn[ii]);
    Qs[((size_t)h * S_LEN + s) * D_QK + 160 + ii] = f2bf_bits(e1 * cs[ii] + e0 * sn[ii]);
  }
#pragma unroll
  for (int p = 0; p < 4; ++p) {
    const int idx = t * 4 + p;          // 0..1023
    const int hh = idx >> 6, ii = idx & 63;
    Ks[((size_t)hh * S_LEN + s) * D_QK + 128 + ii] = krs[ii];
  }
}

// ---------------------------------------------------------------------------
// V transpose via LDS tile: Vt[h][d][s] = kvb[s][h*256+128+d].
// ---------------------------------------------------------------------------
__global__ __launch_bounds__(256)
void vtr_k(const short* __restrict__ kvb, short* __restrict__ Vt) {
  const int st = blockIdx.x, dt = blockIdx.y, h = blockIdx.z;
  __shared__ short sT[64][72];
  const int id = threadIdx.x;
#pragma unroll
  for (int p = 0; p < 2; ++p) {
    const int q = id + p * 256;
    const int row = q >> 3, c8 = q & 7;
    *(short8*)(&sT[row][c8 * 8]) =
        *(const short8*)(kvb + (size_t)(st * 64 + row) * KVB_N + h * 256 + 128 + dt * 64 + c8 * 8);
  }
  __syncthreads();
#pragma unroll
  for (int p = 0; p < 2; ++p) {
    const int q = id + p * 256;
    const int drow = q >> 3, c8 = q & 7;
    short8 o;
#pragma unroll
    for (int j = 0; j < 8; ++j) o[j] = sT[c8 * 8 + j][drow];
    *(short8*)(Vt + ((size_t)h * D_V + dt * 64 + drow) * S_LEN + st * 64 + c8 * 8) = o;
  }
}

// ---------------------------------------------------------------------------
// Flash attention v5: v4 balanced tile-pairing + register-prefetch pipeline.
// Tile jt+1's K/V global loads are issued right after the staging barrier and
// consumed (LDS write) only at the NEXT iteration's top -> ~2000 cyc of
// compute covers the ~400-900 cyc memory latency that v4 exposed per iter.
// launch_bounds(256,1): grid=256 means 1 block/CU; don't choke the allocator.
// ---------------------------------------------------------------------------
__global__ __launch_bounds__(256, 1)
void flash_k(const short* __restrict__ Qs, const short* __restrict__ Ks,
             const short* __restrict__ Vt, short* __restrict__ Oc) {
  __shared__ short sK[64 * 200];        // 25.6 KB
  __shared__ short sVt[128 * 72];       // 18.4 KB
  __shared__ short P_lds[4][16 * 72];   //  9.2 KB
  const int tid = threadIdx.x;
  const int wv = tid >> 6;
  const int lane = tid & 63;
  const int blk = blockIdx.x;                          // 0..255
  const int h = ((blk & 7) << 1) | ((blk >> 3) & 1);   // 2 heads per XCD
  const int a = blk >> 4;                              // light 64-row tile 0..15
  const int b = 31 - a;                                // heavy 64-row tile
  const int fr = lane & 15, g = lane >> 4;
  const int q0[2] = { a * 64 + wv * 16, b * 64 + wv * 16 };

  const short* Qh = Qs + (size_t)h * S_LEN * D_QK;
  const short* Kh = Ks + (size_t)h * S_LEN * D_QK;
  const short* Vh = Vt + (size_t)h * D_V * S_LEN;

  // loop-invariant staging coordinates
  int rowK[6], c8K[6], rowV[4], c8V[4];
#pragma unroll
  for (int p = 0; p < 6; ++p) {
    const int id = tid + p * 256;
    rowK[p] = id / 24; c8K[p] = id % 24;
  }
#pragma unroll
  for (int p = 0; p < 4; ++p) {
    const int id = tid + p * 256;
    rowV[p] = id >> 3; c8V[p] = id & 7;
  }

  short8 qa[2][6];
#pragma unroll
  for (int rt = 0; rt < 2; ++rt)
#pragma unroll
    for (int c = 0; c < 6; ++c)
      qa[rt][c] = *(const short8*)(Qh + (size_t)(q0[rt] + fr) * D_QK + c * 32 + g * 8);

  f32x4 o[2][8];
  float m_i[2][4], l_i[2][4];
#pragma unroll
  for (int rt = 0; rt < 2; ++rt)
#pragma unroll
    for (int r = 0; r < 4; ++r) {
      m_i[rt][r] = -1e30f; l_i[rt][r] = 0.f;
#pragma unroll
      for (int f = 0; f < 8; ++f) o[rt][f][r] = 0.f;
    }

  // prefetch tile 0
  short8 kc[6], vc[4];
#pragma unroll
  for (int p = 0; p < 6; ++p)
    kc[p] = *(const short8*)(Kh + (size_t)rowK[p] * D_QK + c8K[p] * 8);
#pragma unroll
  for (int p = 0; p < 4; ++p)
    vc[p] = *(const short8*)(Vh + (size_t)rowV[p] * S_LEN + c8V[p] * 8);

  short* pl = &P_lds[wv][0];
  const int jn = b + 1;                                // 17..32
  for (int jt = 0; jt < jn; ++jt) {
    const int j0 = jt << 6;
    const bool lightOn = (jt <= a);                    // block-uniform
    // ---- commit prefetched tile to LDS ----
    __syncthreads();
#pragma unroll
    for (int p = 0; p < 6; ++p)
      *(short8*)(sK + rowK[p] * 200 + c8K[p] * 8) = kc[p];
#pragma unroll
    for (int p = 0; p < 4; ++p)
      *(short8*)(sVt + rowV[p] * 72 + c8V[p] * 8) = vc[p];
    __syncthreads();
    // ---- issue next tile's global loads (consumed next iteration) ----
    if (jt + 1 < jn) {
      const int j1 = (jt + 1) << 6;
#pragma unroll
      for (int p = 0; p < 6; ++p)
        kc[p] = *(const short8*)(Kh + (size_t)(j1 + rowK[p]) * D_QK + c8K[p] * 8);
#pragma unroll
      for (int p = 0; p < 4; ++p)
        vc[p] = *(const short8*)(Vh + (size_t)rowV[p] * S_LEN + j1 + c8V[p] * 8);
    }

    // ---- QK^T: K-fragments read ONCE, used for both row-sets ----
    f32x4 sc[2][4];
#pragma unroll
    for (int rt = 0; rt < 2; ++rt)
#pragma unroll
      for (int t = 0; t < 4; ++t)
        for (int r = 0; r < 4; ++r) sc[rt][t][r] = -1e30f;
#pragma unroll
    for (int t = 0; t < 4; ++t) {
      const bool hOn = (j0 + t * 16 <= q0[1] + 15);
      const bool lOn = lightOn && (j0 + t * 16 <= q0[0] + 15);
      if (hOn || lOn) {
        short8 kfr[6];
#pragma unroll
        for (int c = 0; c < 6; ++c)
          kfr[c] = *(const short8*)(sK + (t * 16 + fr) * 200 + c * 32 + g * 8);
        if (lOn) {
          f32x4 acc; for (int r = 0; r < 4; ++r) acc[r] = 0.f;
#pragma unroll
          for (int c = 0; c < 6; ++c) acc = mfma_bf16(qa[0][c], kfr[c], acc);
          sc[0][t] = acc;
        }
        if (hOn) {
          f32x4 acc; for (int r = 0; r < 4; ++r) acc[r] = 0.f;
#pragma unroll
          for (int c = 0; c < 6; ++c) acc = mfma_bf16(qa[1][c], kfr[c], acc);
          sc[1][t] = acc;
        }
      }
    }

    // ---- softmax + P->LDS->A-frag + PV, per row-set ----
#pragma unroll
    for (int rt = 0; rt < 2; ++rt) {
      if (rt == 0 && !lightOn) continue;               // block-uniform
      const int qq = q0[rt];
      float tm[4];
#pragma unroll
      for (int r = 0; r < 4; ++r) {
        const int row = qq + g * 4 + r;
        float mx = -1e30f;
#pragma unroll
        for (int t = 0; t < 4; ++t) {
          const float v = (j0 + t * 16 + fr <= row) ? sc[rt][t][r] * SCALING : -1e30f;
          sc[rt][t][r] = v;
          mx = fmaxf(mx, v);
        }
        tm[r] = mx;
      }
#pragma unroll
      for (int off = 1; off < 16; off <<= 1)
#pragma unroll
        for (int r = 0; r < 4; ++r)
          tm[r] = fmaxf(tm[r], __shfl_xor(tm[r], off, 16));
      float ps[4];
#pragma unroll
      for (int r = 0; r < 4; ++r) {
        const float mnew = fmaxf(m_i[rt][r], tm[r]);
        const float alpha = __expf(m_i[rt][r] - mnew);
        m_i[rt][r] = mnew;
        l_i[rt][r] *= alpha;
        float s = 0.f;
#pragma unroll
        for (int t = 0; t < 4; ++t) {
          const float p = __expf(sc[rt][t][r] - mnew);
          sc[rt][t][r] = p;
          s += p;
        }
        ps[r] = s;
#pragma unroll
        for (int f = 0; f < 8; ++f) o[rt][f][r] *= alpha;
      }
#pragma unroll
      for (int off = 1; off < 16; off <<= 1)
#pragma unroll
        for (int r = 0; r < 4; ++r)
          ps[r] += __shfl_xor(ps[r], off, 16);
#pragma unroll
      for (int r = 0; r < 4; ++r) l_i[rt][r] += ps[r];

#pragma unroll
      for (int r = 0; r < 4; ++r)
#pragma unroll
        for (int t = 0; t < 4; ++t)
          pl[(g * 4 + r) * 72 + t * 16 + fr] = f2bf_bits(sc[rt][t][r]);
      __builtin_amdgcn_fence(__ATOMIC_ACQ_REL, "wavefront");
      const short8 pa0 = *(const short8*)(pl + fr * 72 + g * 8);
      const short8 pa1 = *(const short8*)(pl + fr * 72 + 32 + g * 8);
#pragma unroll
      for (int f = 0; f < 8; ++f) {
        const short* vr = sVt + (f * 16 + fr) * 72 + g * 8;
        const short8 vb0 = *(const short8*)(vr);
        const short8 vb1 = *(const short8*)(vr + 32);
        o[rt][f] = mfma_bf16(pa1, vb1, mfma_bf16(pa0, vb0, o[rt][f]));
      }
    }
  }

#pragma unroll
  for (int rt = 0; rt < 2; ++rt)
#pragma unroll
    for (int r = 0; r < 4; ++r) {
      const float inv = 1.0f / l_i[rt][r];
      const int row = q0[rt] + g * 4 + r;
#pragma unroll
      for (int f = 0; f < 8; ++f)
        Oc[(size_t)row * (NH * D_V) + h * D_V + f * 16 + fr] = f2bf_bits(o[rt][f][r] * inv);
    }
}

// ---------------------------------------------------------------------------
extern "C" void kernel_launch(void* const* d_in, const int* in_sizes, int n_in,
                              void* d_out, int out_size, void* d_ws, size_t ws_size,
                              hipStream_t stream) {
  const float* hidden = (const float*)d_in[0];
  const float* cosb   = (const float*)d_in[1];
  const float* sinb   = (const float*)d_in[2];
  /* d_in[3] attention_mask: causal, applied analytically */
  const float* q_w    = (const float*)d_in[4];
  const float* kva_w  = (const float*)d_in[5];
  const float* ln_w   = (const float*)d_in[6];
  const float* kvb_w  = (const float*)d_in[7];
  const float* o_w    = (const float*)d_in[8];
  float* out = (float*)d_out;

  char* ws = (char*)d_ws;
  size_t off = 0;
  auto alloc = [&](size_t elems) {
    short* p = (short*)(ws + off);
    off += ((elems * 2 + 255) & ~(size_t)255);
    return p;
  };
  short* hid_b   = alloc((size_t)S_LEN * HID_DIM);
  short* qkva_wb = alloc((size_t)CAT_N * HID_DIM);   // q_w rows then kva_w rows
  short* kvb_wb  = alloc((size_t)KVB_N * KV_R);
  short* o_wb    = alloc((size_t)HID_DIM * NH * D_V);
  short* qckv    = alloc((size_t)S_LEN * CAT_N);     // fused q + ckv output
  short* ckvn    = alloc((size_t)S_LEN * KV_R);
  short* kvb     = alloc((size_t)S_LEN * KVB_N);
  short* Qs      = alloc((size_t)NH * S_LEN * D_QK);
  short* Ks      = alloc((size_t)NH * S_LEN * D_QK);
  short* Vt      = alloc((size_t)NH * D_V * S_LEN);
  short* Oc      = alloc((size_t)S_LEN * NH * D_V);

  dim3 blk(256);
  const int n0 = (S_LEN * HID_DIM) / 4;
  const int n1 = (QN * HID_DIM) / 4;
  const int n2 = (CKV_N * HID_DIM) / 4;
  const int n3 = (KVB_N * KV_R) / 4;
  const int n4e = (HID_DIM * NH * D_V) / 4;
  const int c0 = n0, c1 = c0 + n1, c2 = c1 + n2, c3 = c2 + n3, c4 = c3 + n4e;
  cvt5_k<<<dim3((c4 + 255) / 256), blk, 0, stream>>>(
      hidden, hid_b, c0,
      q_w, qkva_wb, c1,
      kva_w, qkva_wb + (size_t)QN * HID_DIM, c2,
      kvb_w, kvb_wb, c3,
      o_w, o_wb, c4);

  gemm_bt<false><<<dim3((CAT_N + 127) / 128, S_LEN / 128), blk, 0, stream>>>(
      hid_b, qkva_wb, qckv, S_LEN, CAT_N, HID_DIM);
  rmsnorm_k<<<dim3(S_LEN), blk, 0, stream>>>(qckv, ln_w, ckvn);
  gemm_bt<false><<<dim3(KVB_N / 128, S_LEN / 128), blk, 0, stream>>>(
      ckvn, kvb_wb, kvb, S_LEN, KVB_N, KV_R);
  prep_k<<<dim3(S_LEN), blk, 0, stream>>>(qckv, kvb, cosb, sinb, Qs, Ks);
  vtr_k<<<dim3(S_LEN / 64, D_V / 64, NH), blk, 0, stream>>>(kvb, Vt);
  flash_k<<<dim3(NH * 16), blk, 0, stream>>>(Qs, Ks, Vt, Oc);
  gemm_bt<true><<<dim3(HID_DIM / 128, S_LEN / 128), blk, 0, stream>>>(
      Oc, o_wb, out, S_LEN, HID_DIM, NH * D_V);
}

// Round 9
// 317.744 us; speedup vs baseline: 1.0105x; 1.0105x over previous
//
#include <hip/hip_runtime.h>
#include <hip/hip_bf16.h>
#include <stdint.h>
#include <stddef.h>

#define S_LEN 2048
#define HID_DIM 2048
#define NH 16
#define D_QK 192
#define D_NOPE 128
#define D_ROPE 64
#define D_V 128
#define KV_R 512
#define CKV_N (KV_R + D_ROPE)            /* 576 */
#define KVB_N (NH * (D_NOPE + D_V))      /* 4096 */
#define QN (NH * D_QK)                   /* 3072 */
#define CAT_N (QN + CKV_N)               /* 3648: q_proj+kv_a fused N */
#define SCALING 0.07216878364870322f     /* 192^-0.5 */

typedef __attribute__((ext_vector_type(8))) short short8;
typedef __attribute__((ext_vector_type(4))) short short4v;
typedef __attribute__((ext_vector_type(4))) float f32x4;

__device__ __forceinline__ short f2bf_bits(float f) {
  unsigned u = __float_as_uint(f);
  unsigned r = (u + 0x7fffu + ((u >> 16) & 1u)) >> 16;  // RNE
  return (short)(r & 0xffffu);
}
__device__ __forceinline__ float bf2f(short b) {
  return __uint_as_float(((unsigned)(unsigned short)b) << 16);
}

__device__ __forceinline__ f32x4 mfma_bf16(short8 a, short8 b, f32x4 c) {
  return __builtin_amdgcn_mfma_f32_16x16x32_bf16(a, b, c, 0, 0, 0);
}

// ---------------------------------------------------------------------------
// Fused f32 -> bf16 conversion of 5 tensors in one launch.
// ---------------------------------------------------------------------------
__global__ __launch_bounds__(256)
void cvt5_k(const float* __restrict__ s0, short* __restrict__ d0, int c0,
            const float* __restrict__ s1, short* __restrict__ d1, int c1,
            const float* __restrict__ s2, short* __restrict__ d2, int c2,
            const float* __restrict__ s3, short* __restrict__ d3, int c3,
            const float* __restrict__ s4, short* __restrict__ d4, int c4) {
  const int i = blockIdx.x * 256 + threadIdx.x;
  const float* s; short* d; int base;
  if      (i < c0) { s = s0; d = d0; base = 0;  }
  else if (i < c1) { s = s1; d = d1; base = c0; }
  else if (i < c2) { s = s2; d = d2; base = c1; }
  else if (i < c3) { s = s3; d = d3; base = c2; }
  else if (i < c4) { s = s4; d = d4; base = c3; }
  else return;
  const int j = i - base;
  const float4 v = ((const float4*)s)[j];
  short4v o;
  o.x = f2bf_bits(v.x); o.y = f2bf_bits(v.y);
  o.z = f2bf_bits(v.z); o.w = f2bf_bits(v.w);
  ((short4v*)d)[j] = o;
}

// ---------------------------------------------------------------------------
// C[M,N] = A[M,K] @ B[N,K]^T   (A,B bf16 bits, f32 accum). BK=64 (2x m97).
// ---------------------------------------------------------------------------
template <bool OUTF32>
__global__ __launch_bounds__(256, 3)
void gemm_bt(const short* __restrict__ A, const short* __restrict__ B,
             void* __restrict__ Cv, int M, int N, int K) {
  __shared__ short sA[2][128 * 32];
  __shared__ short sB[2][128 * 32];
  const int tid  = threadIdx.x;
  const int wave = tid >> 6;
  const int lane = tid & 63;
  const int bm = blockIdx.y * 128;
  const int bn = blockIdx.x * 128;
  const int wr = wave >> 1, wc = wave & 1;
  const int fr = lane & 15, fk = (lane >> 4) * 8;
  const int srow = lane >> 2;
  const int scol = (lane & 3) * 8;

  f32x4 acc[4][4];
  for (int i = 0; i < 4; ++i)
    for (int j = 0; j < 4; ++j)
      for (int r = 0; r < 4; ++r) acc[i][j][r] = 0.f;

  for (int k0 = 0; k0 < K; k0 += 64) {
    __syncthreads();
#pragma unroll
    for (int cc = 0; cc < 2; ++cc) {
      const int c = wave * 2 + cc;
      const int ar = bm + c * 16 + srow;
      int br = bn + c * 16 + srow; if (br > N - 1) br = N - 1;
#pragma unroll
      for (int kh = 0; kh < 2; ++kh) {
        __builtin_amdgcn_global_load_lds(
            (const __attribute__((address_space(1))) void*)(A + (size_t)ar * K + k0 + kh * 32 + scol),
            (__attribute__((address_space(3))) void*)(sA[kh] + c * 512), 16, 0, 0);
        __builtin_amdgcn_global_load_lds(
            (const __attribute__((address_space(1))) void*)(B + (size_t)br * K + k0 + kh * 32 + scol),
            (__attribute__((address_space(3))) void*)(sB[kh] + c * 512), 16, 0, 0);
      }
    }
    __syncthreads();
#pragma unroll
    for (int kh = 0; kh < 2; ++kh) {
      short8 af[4], bfr[4];
#pragma unroll
      for (int i = 0; i < 4; ++i)
        af[i] = *(const short8*)(sA[kh] + (wr * 64 + i * 16 + fr) * 32 + fk);
#pragma unroll
      for (int j = 0; j < 4; ++j)
        bfr[j] = *(const short8*)(sB[kh] + (wc * 64 + j * 16 + fr) * 32 + fk);
#pragma unroll
      for (int i = 0; i < 4; ++i)
#pragma unroll
        for (int j = 0; j < 4; ++j)
          acc[i][j] = mfma_bf16(af[i], bfr[j], acc[i][j]);
    }
  }

  const int cr = (lane >> 4) * 4, ccol = lane & 15;
#pragma unroll
  for (int i = 0; i < 4; ++i)
#pragma unroll
    for (int j = 0; j < 4; ++j) {
      const int col = bn + wc * 64 + j * 16 + ccol;
      if (col < N) {
#pragma unroll
        for (int r = 0; r < 4; ++r) {
          const int row = bm + wr * 64 + i * 16 + cr + r;
          if (OUTF32)
            ((float*)Cv)[(size_t)row * N + col] = acc[i][j][r];
          else
            ((short*)Cv)[(size_t)row * N + col] = f2bf_bits(acc[i][j][r]);
        }
      }
    }
}

// ---------------------------------------------------------------------------
// RMSNorm over qckv[:, 3072:3584] -> ckvn (bf16).
// ---------------------------------------------------------------------------
__global__ __launch_bounds__(256)
void rmsnorm_k(const short* __restrict__ qckv, const float* __restrict__ w,
               short* __restrict__ out) {
  const int s = blockIdx.x, t = threadIdx.x;
  const short* x = qckv + (size_t)s * CAT_N + QN;
  float v0 = bf2f(x[2 * t]), v1 = bf2f(x[2 * t + 1]);
  float ss = v0 * v0 + v1 * v1;
#pragma unroll
  for (int off = 1; off < 64; off <<= 1) ss += __shfl_xor(ss, off, 64);
  __shared__ float red[4];
  if ((t & 63) == 0) red[t >> 6] = ss;
  __syncthreads();
  const float tot = red[0] + red[1] + red[2] + red[3];
  const float sc = rsqrtf(tot * (1.0f / 512.0f) + 1e-6f);
  out[(size_t)s * KV_R + 2 * t]     = f2bf_bits(v0 * sc * w[2 * t]);
  out[(size_t)s * KV_R + 2 * t + 1] = f2bf_bits(v1 * sc * w[2 * t + 1]);
}

// ---------------------------------------------------------------------------
// Prep: RoPE (deinterleaved) + assemble Qs[h][s][192], Ks[h][s][192].
// ---------------------------------------------------------------------------
__global__ __launch_bounds__(256)
void prep_k(const short* __restrict__ qckv, const short* __restrict__ kvb,
            const float* __restrict__ cosb, const float* __restrict__ sinb,
            short* __restrict__ Qs, short* __restrict__ Ks) {
  const int s = blockIdx.x, t = threadIdx.x;
  const short* qrow = qckv + (size_t)s * CAT_N;
  __shared__ float cs[32], sn[32];
  __shared__ short krs[64];
  if (t < 32) {
    const float c  = cosb[(size_t)s * 64 + t];
    const float si = sinb[(size_t)s * 64 + t];
    cs[t] = c; sn[t] = si;
    const float e0 = bf2f(qrow[QN + KV_R + 2 * t]);
    const float e1 = bf2f(qrow[QN + KV_R + 2 * t + 1]);
    krs[t]      = f2bf_bits(e0 * c - e1 * si);
    krs[t + 32] = f2bf_bits(e1 * c + e0 * si);
  }
  __syncthreads();
  const int h = t >> 4, i = t & 15;
  *(short8*)(Qs + ((size_t)h * S_LEN + s) * D_QK + i * 8) =
      *(const short8*)(qrow + h * D_QK + i * 8);
  *(short8*)(Ks + ((size_t)h * S_LEN + s) * D_QK + i * 8) =
      *(const short8*)(kvb + (size_t)s * KVB_N + h * 256 + i * 8);
#pragma unroll
  for (int p = 0; p < 2; ++p) {
    const int ii = i * 2 + p;  // 0..31
    const float e0 = bf2f(qrow[h * D_QK + 128 + 2 * ii]);
    const float e1 = bf2f(qrow[h * D_QK + 128 + 2 * ii + 1]);
    Qs[((size_t)h * S_LEN + s) * D_QK + 128 + ii] = f2bf_bits(e0 * cs[ii] - e1 * sn[ii]);
    Qs[((size_t)h * S_LEN + s) * D_QK + 160 + ii] = f2bf_bits(e1 * cs[ii] + e0 * sn[ii]);
  }
#pragma unroll
  for (int p = 0; p < 4; ++p) {
    const int idx = t * 4 + p;          // 0..1023
    const int hh = idx >> 6, ii = idx & 63;
    Ks[((size_t)hh * S_LEN + s) * D_QK + 128 + ii] = krs[ii];
  }
}

// ---------------------------------------------------------------------------
// V transpose via LDS tile: Vt[h][d][s] = kvb[s][h*256+128+d].
// ---------------------------------------------------------------------------
__global__ __launch_bounds__(256)
void vtr_k(const short* __restrict__ kvb, short* __restrict__ Vt) {
  const int st = blockIdx.x, dt = blockIdx.y, h = blockIdx.z;
  __shared__ short sT[64][72];
  const int id = threadIdx.x;
#pragma unroll
  for (int p = 0; p < 2; ++p) {
    const int q = id + p * 256;
    const int row = q >> 3, c8 = q & 7;
    *(short8*)(&sT[row][c8 * 8]) =
        *(const short8*)(kvb + (size_t)(st * 64 + row) * KVB_N + h * 256 + 128 + dt * 64 + c8 * 8);
  }
  __syncthreads();
#pragma unroll
  for (int p = 0; p < 2; ++p) {
    const int q = id + p * 256;
    const int drow = q >> 3, c8 = q & 7;
    short8 o;
#pragma unroll
    for (int j = 0; j < 8; ++j) o[j] = sT[c8 * 8 + j][drow];
    *(short8*)(Vt + ((size_t)h * D_V + dt * 64 + drow) * S_LEN + st * 64 + c8 * 8) = o;
  }
}

// ---------------------------------------------------------------------------
// Flash attention v6 = v3b mapping (512 blocks, one 64-row q-tile per block,
// heavy-first, 2 blocks/CU for TLP) + v5's register-prefetch pipeline
// (next tile's K/V global loads issued after the staging barrier, consumed
// at the next iteration's LDS-commit -> staging latency covered by compute
// AND by the co-resident block).
// ---------------------------------------------------------------------------
__global__ __launch_bounds__(256, 2)
void flash_k(const short* __restrict__ Qs, const short* __restrict__ Ks,
             const short* __restrict__ Vt, short* __restrict__ Oc) {
  __shared__ short sK[64 * 200];        // 25.6 KB
  __shared__ short sVt[128 * 72];       // 18.4 KB
  __shared__ short P_lds[4][16 * 72];   //  9.2 KB
  const int tid = threadIdx.x;
  const int wv = tid >> 6;
  const int lane = tid & 63;
  const int blk = blockIdx.x;                          // 0..511
  const int h = ((blk & 7) << 1) | ((blk >> 3) & 1);   // 2 heads per XCD
  const int qb = 31 - (blk >> 4);                      // heavy q-blocks first
  const int q0 = qb * 64 + wv * 16;
  const int fr = lane & 15, g = lane >> 4;

  const short* Qh = Qs + (size_t)h * S_LEN * D_QK;
  const short* Kh = Ks + (size_t)h * S_LEN * D_QK;
  const short* Vh = Vt + (size_t)h * D_V * S_LEN;

  // loop-invariant staging coordinates
  int rowK[6], c8K[6], rowV[4], c8V[4];
#pragma unroll
  for (int p = 0; p < 6; ++p) {
    const int id = tid + p * 256;
    rowK[p] = id / 24; c8K[p] = id % 24;
  }
#pragma unroll
  for (int p = 0; p < 4; ++p) {
    const int id = tid + p * 256;
    rowV[p] = id >> 3; c8V[p] = id & 7;
  }

  short8 qa[6];
#pragma unroll
  for (int c = 0; c < 6; ++c)
    qa[c] = *(const short8*)(Qh + (size_t)(q0 + fr) * D_QK + c * 32 + g * 8);

  f32x4 o[8];
  for (int f = 0; f < 8; ++f)
    for (int r = 0; r < 4; ++r) o[f][r] = 0.f;
  float m_i[4] = {-1e30f, -1e30f, -1e30f, -1e30f};
  float l_i[4] = {0.f, 0.f, 0.f, 0.f};

  // prefetch tile 0
  short8 kc[6], vc[4];
#pragma unroll
  for (int p = 0; p < 6; ++p)
    kc[p] = *(const short8*)(Kh + (size_t)rowK[p] * D_QK + c8K[p] * 8);
#pragma unroll
  for (int p = 0; p < 4; ++p)
    vc[p] = *(const short8*)(Vh + (size_t)rowV[p] * S_LEN + c8V[p] * 8);

  short* pl = &P_lds[wv][0];
  const int jn = qb + 1;
  for (int jt = 0; jt < jn; ++jt) {
    const int j0 = jt << 6;
    // ---- commit prefetched tile to LDS ----
    __syncthreads();
#pragma unroll
    for (int p = 0; p < 6; ++p)
      *(short8*)(sK + rowK[p] * 200 + c8K[p] * 8) = kc[p];
#pragma unroll
    for (int p = 0; p < 4; ++p)
      *(short8*)(sVt + rowV[p] * 72 + c8V[p] * 8) = vc[p];
    __syncthreads();
    // ---- issue next tile's global loads (consumed next iteration) ----
    if (jt + 1 < jn) {
      const int j1 = (jt + 1) << 6;
#pragma unroll
      for (int p = 0; p < 6; ++p)
        kc[p] = *(const short8*)(Kh + (size_t)(j1 + rowK[p]) * D_QK + c8K[p] * 8);
#pragma unroll
      for (int p = 0; p < 4; ++p)
        vc[p] = *(const short8*)(Vh + (size_t)rowV[p] * S_LEN + j1 + c8V[p] * 8);
    }

    // ---- QK^T from LDS; skip fully-masked 16-key sub-tiles (wave-uniform) --
    f32x4 sc[4];
#pragma unroll
    for (int t = 0; t < 4; ++t)
      for (int r = 0; r < 4; ++r) sc[t][r] = -1e30f;
#pragma unroll
    for (int t = 0; t < 4; ++t) {
      if (j0 + t * 16 <= q0 + 15) {
        f32x4 a;
        for (int r = 0; r < 4; ++r) a[r] = 0.f;
        const short* kr = sK + (t * 16 + fr) * 200 + g * 8;
#pragma unroll
        for (int c = 0; c < 6; ++c)
          a = mfma_bf16(qa[c], *(const short8*)(kr + c * 32), a);
        sc[t] = a;
      }
    }
    // ---- scale + causal mask + per-row tile max ----
    float tm[4];
#pragma unroll
    for (int r = 0; r < 4; ++r) {
      const int row = q0 + g * 4 + r;
      float mx = -1e30f;
#pragma unroll
      for (int t = 0; t < 4; ++t) {
        const float v = (j0 + t * 16 + fr <= row) ? sc[t][r] * SCALING : -1e30f;
        sc[t][r] = v;
        mx = fmaxf(mx, v);
      }
      tm[r] = mx;
    }
#pragma unroll
    for (int off = 1; off < 16; off <<= 1)
#pragma unroll
      for (int r = 0; r < 4; ++r)
        tm[r] = fmaxf(tm[r], __shfl_xor(tm[r], off, 16));
    // ---- online softmax update ----
    float ps[4];
#pragma unroll
    for (int r = 0; r < 4; ++r) {
      const float mnew = fmaxf(m_i[r], tm[r]);
      const float alpha = __expf(m_i[r] - mnew);
      m_i[r] = mnew;
      l_i[r] *= alpha;
      float s = 0.f;
#pragma unroll
      for (int t = 0; t < 4; ++t) {
        const float p = __expf(sc[t][r] - mnew);
        sc[t][r] = p;
        s += p;
      }
      ps[r] = s;
#pragma unroll
      for (int f = 0; f < 8; ++f) o[f][r] *= alpha;
    }
#pragma unroll
    for (int off = 1; off < 16; off <<= 1)
#pragma unroll
      for (int r = 0; r < 4; ++r)
        ps[r] += __shfl_xor(ps[r], off, 16);
#pragma unroll
    for (int r = 0; r < 4; ++r) l_i[r] += ps[r];

    // ---- P (C-layout) -> per-wave LDS -> A-frag ----
#pragma unroll
    for (int r = 0; r < 4; ++r)
#pragma unroll
      for (int t = 0; t < 4; ++t)
        pl[(g * 4 + r) * 72 + t * 16 + fr] = f2bf_bits(sc[t][r]);
    __builtin_amdgcn_fence(__ATOMIC_ACQ_REL, "wavefront");
    const short8 pa0 = *(const short8*)(pl + fr * 72 + g * 8);
    const short8 pa1 = *(const short8*)(pl + fr * 72 + 32 + g * 8);

    // ---- PV from LDS V^T tile ----
#pragma unroll
    for (int f = 0; f < 8; ++f) {
      const short* vr = sVt + (f * 16 + fr) * 72 + g * 8;
      const short8 vb0 = *(const short8*)(vr);
      const short8 vb1 = *(const short8*)(vr + 32);
      o[f] = mfma_bf16(pa1, vb1, mfma_bf16(pa0, vb0, o[f]));
    }
  }

#pragma unroll
  for (int r = 0; r < 4; ++r) {
    const float inv = 1.0f / l_i[r];
    const int row = q0 + g * 4 + r;
#pragma unroll
    for (int f = 0; f < 8; ++f)
      Oc[(size_t)row * (NH * D_V) + h * D_V + f * 16 + fr] = f2bf_bits(o[f][r] * inv);
  }
}

// ---------------------------------------------------------------------------
extern "C" void kernel_launch(void* const* d_in, const int* in_sizes, int n_in,
                              void* d_out, int out_size, void* d_ws, size_t ws_size,
                              hipStream_t stream) {
  const float* hidden = (const float*)d_in[0];
  const float* cosb   = (const float*)d_in[1];
  const float* sinb   = (const float*)d_in[2];
  /* d_in[3] attention_mask: causal, applied analytically */
  const float* q_w    = (const float*)d_in[4];
  const float* kva_w  = (const float*)d_in[5];
  const float* ln_w   = (const float*)d_in[6];
  const float* kvb_w  = (const float*)d_in[7];
  const float* o_w    = (const float*)d_in[8];
  float* out = (float*)d_out;

  char* ws = (char*)d_ws;
  size_t off = 0;
  auto alloc = [&](size_t elems) {
    short* p = (short*)(ws + off);
    off += ((elems * 2 + 255) & ~(size_t)255);
    return p;
  };
  short* hid_b   = alloc((size_t)S_LEN * HID_DIM);
  short* qkva_wb = alloc((size_t)CAT_N * HID_DIM);   // q_w rows then kva_w rows
  short* kvb_wb  = alloc((size_t)KVB_N * KV_R);
  short* o_wb    = alloc((size_t)HID_DIM * NH * D_V);
  short* qckv    = alloc((size_t)S_LEN * CAT_N);     // fused q + ckv output
  short* ckvn    = alloc((size_t)S_LEN * KV_R);
  short* kvb     = alloc((size_t)S_LEN * KVB_N);
  short* Qs      = alloc((size_t)NH * S_LEN * D_QK);
  short* Ks      = alloc((size_t)NH * S_LEN * D_QK);
  short* Vt      = alloc((size_t)NH * D_V * S_LEN);
  short* Oc      = alloc((size_t)S_LEN * NH * D_V);

  dim3 blk(256);
  const int n0 = (S_LEN * HID_DIM) / 4;
  const int n1 = (QN * HID_DIM) / 4;
  const int n2 = (CKV_N * HID_DIM) / 4;
  const int n3 = (KVB_N * KV_R) / 4;
  const int n4e = (HID_DIM * NH * D_V) / 4;
  const int c0 = n0, c1 = c0 + n1, c2 = c1 + n2, c3 = c2 + n3, c4 = c3 + n4e;
  cvt5_k<<<dim3((c4 + 255) / 256), blk, 0, stream>>>(
      hidden, hid_b, c0,
      q_w, qkva_wb, c1,
      kva_w, qkva_wb + (size_t)QN * HID_DIM, c2,
      kvb_w, kvb_wb, c3,
      o_w, o_wb, c4);

  gemm_bt<false><<<dim3((CAT_N + 127) / 128, S_LEN / 128), blk, 0, stream>>>(
      hid_b, qkva_wb, qckv, S_LEN, CAT_N, HID_DIM);
  rmsnorm_k<<<dim3(S_LEN), blk, 0, stream>>>(qckv, ln_w, ckvn);
  gemm_bt<false><<<dim3(KVB_N / 128, S_LEN / 128), blk, 0, stream>>>(
      ckvn, kvb_wb, kvb, S_LEN, KVB_N, KV_R);
  prep_k<<<dim3(S_LEN), blk, 0, stream>>>(qckv, kvb, cosb, sinb, Qs, Ks);
  vtr_k<<<dim3(S_LEN / 64, D_V / 64, NH), blk, 0, stream>>>(kvb, Vt);
  flash_k<<<dim3(NH * 128 / 4), blk, 0, stream>>>(Qs, Ks, Vt, Oc);
  gemm_bt<true><<<dim3(HID_DIM / 128, S_LEN / 128), blk, 0, stream>>>(
      Oc, o_wb, out, S_LEN, HID_DIM, NH * D_V);
}